// Round 15
// baseline (97.860 us; speedup 1.0000x reference)
//
#include <hip/hip_runtime.h>

typedef __attribute__((ext_vector_type(4))) float f32x4;
typedef __attribute__((ext_vector_type(8))) short s16x8;
typedef unsigned int u32;
typedef __attribute__((ext_vector_type(4))) unsigned int u32x4;

#define B_ 2
#define N_ 2048
#define C_ 1024
#define H_ 16
#define D_ 64

__device__ __forceinline__ unsigned short f2bf(float f) {
  union { float f; unsigned u; } v; v.f = f;
  unsigned r = v.u + 0x7fffu + ((v.u >> 16) & 1u);
  return (unsigned short)(r >> 16);
}

// ---------------------------------------------------------------------------
// Blocks [0,1024): transpose + convert weights to bf16 (Wq gets 1/8*log2e).
// Blocks [1024,3072): convert x (f32) -> xb (bf16), 2048 elems/block.
// ---------------------------------------------------------------------------
__global__ __launch_bounds__(256) void wtrans_kernel(
    const float* __restrict__ Wq, const float* __restrict__ Wk,
    const float* __restrict__ Wv, const float* __restrict__ Wo,
    unsigned short* __restrict__ WtQKV, unsigned short* __restrict__ WtO,
    const float* __restrict__ xsrc, unsigned short* __restrict__ xb) {
  const int t = threadIdx.x;
  if (blockIdx.x >= 1024) {
    int i = (blockIdx.x - 1024) * 2048 + t * 8;
    float4 f0 = *(const float4*)&xsrc[i];
    float4 f1 = *(const float4*)&xsrc[i + 4];
    u32 p0, p1, p2, p3;
    asm("v_cvt_pk_bf16_f32 %0, %1, %2" : "=v"(p0) : "v"(f0.x), "v"(f0.y));
    asm("v_cvt_pk_bf16_f32 %0, %1, %2" : "=v"(p1) : "v"(f0.z), "v"(f0.w));
    asm("v_cvt_pk_bf16_f32 %0, %1, %2" : "=v"(p2) : "v"(f1.x), "v"(f1.y));
    asm("v_cvt_pk_bf16_f32 %0, %1, %2" : "=v"(p3) : "v"(f1.z), "v"(f1.w));
    uint4 o; o.x = p0; o.y = p1; o.z = p2; o.w = p3;
    *(uint4*)&xb[i] = o;
    return;
  }
  __shared__ float lds[64][65];
  const int w = blockIdx.x >> 8;
  const int tile = blockIdx.x & 255;
  const int c0 = (tile >> 4) * 64, d0 = (tile & 15) * 64;
  const float* W = (w == 0) ? Wq : (w == 1) ? Wk : (w == 2) ? Wv : Wo;
  const float scale = (w == 0) ? 0.125f * 1.4426950408889634f : 1.0f;
  #pragma unroll
  for (int p = 0; p < 16; ++p) {
    int i = p * 256 + t; int r = i >> 6, cc = i & 63;
    lds[r][cc] = W[(size_t)(c0 + r) * 1024 + d0 + cc];
  }
  __syncthreads();
  #pragma unroll
  for (int p = 0; p < 16; ++p) {
    int i = p * 256 + t; int r = i >> 6, cc = i & 63;
    unsigned short v = f2bf(lds[cc][r] * scale);
    if (w < 3) WtQKV[(size_t)(w * 1024 + d0 + r) * 1024 + c0 + cc] = v;
    else       WtO[(size_t)(d0 + r) * 1024 + c0 + cc] = v;
  }
}

// ---------------------------------------------------------------------------
// gemm0: 256x256-tile 8-phase pipelined GEMM (QKV projection), r14-verified
// pipeline. NEW this round: Q/K epilogue goes through a swizzled 256x256 LDS
// transpose buffer (same algebra as the verified V path) and emits b128
// stores (8 consecutive dd per thread) instead of 128 scalar 2B scatters.
// ---------------------------------------------------------------------------
__global__ __launch_bounds__(512, 2) void gemm0_kernel(
    const unsigned short* __restrict__ A, const unsigned short* __restrict__ Bt,
    unsigned short* __restrict__ Qh, unsigned short* __restrict__ Kh,
    unsigned short* __restrict__ Vt) {
  __shared__ __align__(16) unsigned short GS[65536];  // 128KB
  const int tid = threadIdx.x;
  const int lane = tid & 63, wv = tid >> 6;
  const int g = lane >> 4, c = lane & 15;
  const int c7 = c & 7;
  const int wr = wv >> 2, wc = wv & 3;  // 2M x 4N
  const int am0 = blockIdx.x * 256;
  const int bn0 = blockIdx.y * 256;
  const int srow8 = lane >> 3;
  const int schunk = (lane & 7) ^ (srow8 & 7);  // involution source swizzle

  enum { A0o = 0, A1o = 16384, B0o = 32768, B1o = 49152 };

  f32x4 acc[8][4];
  #pragma unroll
  for (int m = 0; m < 8; ++m)
    #pragma unroll
    for (int n = 0; n < 4; ++n) acc[m][n] = (f32x4){0.f, 0.f, 0.f, 0.f};

  s16x8 af[4][2];
  s16x8 bfr[4][2];

#define STAGE(P, rb, ldsOff, h, kslab)                                         \
  do {                                                                         \
    _Pragma("unroll")                                                          \
    for (int i_ = 0; i_ < 2; ++i_) {                                           \
      __builtin_amdgcn_global_load_lds(                                        \
          (const __attribute__((address_space(1))) void*)(                     \
              (P) + (size_t)((rb) + (h) * 128 + i_ * 64 + wv * 8 + srow8) *    \
                        1024 + (kslab) * 64 + schunk * 8),                     \
          (__attribute__((address_space(3))) void*)(GS + (ldsOff) +            \
              ((h) * 128 + i_ * 64 + wv * 8) * 64),                            \
          16, 0, 0);                                                           \
    }                                                                          \
  } while (0)

#define LDA(bufOff, mh)                                                        \
  do {                                                                         \
    _Pragma("unroll")                                                          \
    for (int mm = 0; mm < 4; ++mm)                                             \
      _Pragma("unroll")                                                        \
      for (int kk = 0; kk < 2; ++kk)                                           \
        af[mm][kk] = *(const s16x8*)&GS[(bufOff) +                             \
            (((mh) * 4 + mm) * 32 + wr * 16 + c) * 64 +                        \
            (((kk * 4 + g) ^ c7) << 3)];                                       \
  } while (0)

#define LDB(bufOff, nh)                                                        \
  do {                                                                         \
    _Pragma("unroll")                                                          \
    for (int nn = 0; nn < 2; ++nn)                                             \
      _Pragma("unroll")                                                        \
      for (int kk = 0; kk < 2; ++kk)                                           \
        bfr[(nh) * 2 + nn][kk] = *(const s16x8*)&GS[(bufOff) +                 \
            ((((nh) * 2 + nn) * 64 + wc * 16 + c)) * 64 +                      \
            (((kk * 4 + g) ^ c7) << 3)];                                       \
  } while (0)

#define MM(mh, nh)                                                             \
  do {                                                                         \
    __builtin_amdgcn_s_setprio(1);                                             \
    _Pragma("unroll")                                                          \
    for (int mm = 0; mm < 4; ++mm)                                             \
      _Pragma("unroll")                                                        \
      for (int nn = 0; nn < 2; ++nn)                                           \
        _Pragma("unroll")                                                      \
        for (int kk = 0; kk < 2; ++kk)                                         \
          acc[(mh) * 4 + mm][(nh) * 2 + nn] =                                  \
              __builtin_amdgcn_mfma_f32_16x16x32_bf16(                         \
                  af[mm][kk], bfr[(nh) * 2 + nn][kk],                          \
                  acc[(mh) * 4 + mm][(nh) * 2 + nn], 0, 0, 0);                 \
    __builtin_amdgcn_s_setprio(0);                                             \
  } while (0)

#define BAR() __builtin_amdgcn_s_barrier()
#define LGKM0() asm volatile("s_waitcnt lgkmcnt(0)" ::: "memory")

  STAGE(A, am0, A0o, 0, 0);
  STAGE(Bt, bn0, B0o, 0, 0);
  STAGE(A, am0, A0o, 1, 0);
  STAGE(Bt, bn0, B0o, 1, 0);
  STAGE(A, am0, A1o, 0, 1);
  STAGE(Bt, bn0, B1o, 0, 1);
  STAGE(A, am0, A1o, 1, 1);
  asm volatile("s_waitcnt vmcnt(6)" ::: "memory");
  BAR();

  for (int it = 0; it < 8; ++it) {
    const int kc = 2 * it + 2, kd = 2 * it + 3;
    const bool more = (it < 7);
    LDA(A0o, 0); LDB(B0o, 0);
    STAGE(Bt, bn0, B1o, 1, 2 * it + 1);
    BAR(); LGKM0(); MM(0, 0); BAR();
    LDB(B0o, 1);
    if (more) STAGE(A, am0, A0o, 0, kc);
    BAR(); LGKM0(); MM(0, 1); BAR();
    LDA(A0o, 1);
    if (more) STAGE(Bt, bn0, B0o, 0, kc);
    BAR(); LGKM0(); MM(1, 0); BAR();
    if (more) {
      STAGE(A, am0, A0o, 1, kc);
      asm volatile("s_waitcnt vmcnt(6)" ::: "memory");
    } else {
      asm volatile("s_waitcnt vmcnt(0)" ::: "memory");
    }
    BAR(); LGKM0(); MM(1, 1); BAR();
    LDA(A1o, 0); LDB(B1o, 0);
    if (more) STAGE(Bt, bn0, B0o, 1, kc);
    BAR(); LGKM0(); MM(0, 0); BAR();
    LDB(B1o, 1);
    if (more) STAGE(A, am0, A1o, 0, kd);
    BAR(); LGKM0(); MM(0, 1); BAR();
    LDA(A1o, 1);
    if (more) STAGE(Bt, bn0, B1o, 0, kd);
    BAR(); LGKM0(); MM(1, 0); BAR();
    if (more) {
      STAGE(A, am0, A1o, 1, kd);
      asm volatile("s_waitcnt vmcnt(6)" ::: "memory");
    }
    BAR(); LGKM0(); MM(1, 1); BAR();
  }
#undef STAGE
#undef LDA
#undef LDB
#undef MM
#undef BAR
#undef LGKM0

  const bool vblock = (blockIdx.y >= 8);
  __syncthreads();  // staging regions dead; GS becomes the transpose buffer
  if (!vblock) {
    // Q/K tile: stage C into swizzled LDS, emit b128 rows of Qh/Kh.
    // write (lr,lc) -> GS[lr*256 + ((lc>>3)^(lr&31))*8 + (lc&7)]
    #pragma unroll
    for (int m = 0; m < 8; ++m) {
      #pragma unroll
      for (int n = 0; n < 4; ++n) {
        f32x4 v = acc[m][n];
        int lc = n * 64 + wc * 16 + c;
        int sw = ((lc >> 3) ^ 0) << 3 | (lc & 7);  // lr-dependent xor applied below
        #pragma unroll
        for (int r = 0; r < 4; ++r) {
          int lr = m * 32 + wr * 16 + g * 4 + r;
          GS[lr * 256 + ((((lc >> 3) ^ (lr & 31)) << 3) | (lc & 7))] = f2bf(v[r]);
        }
        (void)sw;
      }
    }
    __syncthreads();
    const int tensor = bn0 >> 10;              // constant per tile (bn0 % 256 == 0)
    const int bb = am0 >> 11;                  // constant per tile (2048 % 256 == 0)
    const int cpos = tid & 31;                 // dd-chunk index within 256 cols
    const int colg = (bn0 & 1023) + cpos * 8;
    const int hh = colg >> 6, dd0 = colg & 63;
    #pragma unroll
    for (int j = 0; j < 16; ++j) {
      int lr = j * 16 + (tid >> 5);
      s16x8 val = *(const s16x8*)&GS[lr * 256 + ((cpos ^ (lr & 31)) << 3)];
      int tok = (am0 & 2047) + lr;
      size_t off = (((size_t)bb * H_ + hh) * N_ + tok) * D_ + dd0;
      if (tensor == 0) *(s16x8*)&Qh[off] = val;
      else             *(s16x8*)&Kh[off] = val;
    }
  } else {
    // V-tile: transpose 256x256 through swizzled LDS, b128 Vt row writes.
    #pragma unroll
    for (int m = 0; m < 8; ++m) {
      #pragma unroll
      for (int n = 0; n < 4; ++n) {
        f32x4 v = acc[m][n];
        int lc = n * 64 + wc * 16 + c;
        #pragma unroll
        for (int r = 0; r < 4; ++r) {
          int lr = m * 32 + wr * 16 + g * 4 + r;
          GS[lc * 256 + ((((lr >> 3) ^ (lc & 31)) << 3) | (lr & 7))] = f2bf(v[r]);
        }
      }
    }
    __syncthreads();
    const int chl = tid & 31, rowb = tid >> 5;  // 32 chunks x 16 row-groups
    const int tok0 = (am0 & 2047) + chl * 8;
    const int bb = am0 >> 11;
    #pragma unroll
    for (int j = 0; j < 16; ++j) {
      int ddl = j * 16 + rowb;
      s16x8 val = *(const s16x8*)&GS[ddl * 256 + ((chl ^ (ddl & 31)) << 3)];
      int vcol = bn0 - 2048 + ddl;
      int hh = vcol >> 6, dd = vcol & 63;
      *(s16x8*)&Vt[(((size_t)bb * H_ + hh) * D_ + dd) * N_ + tok0] = val;
    }
  }
}

// ---------------------------------------------------------------------------
// gemm1 (r13/r14-verified): out[4096][1024] = heads * WtO^T.
// 128x128 tile, BK=32, tri-buffered counted-vmcnt pipeline.
// ---------------------------------------------------------------------------
__global__ __launch_bounds__(256, 3) void gemm1_kernel(
    const unsigned short* __restrict__ A, const unsigned short* __restrict__ Bt,
    float* __restrict__ Cf) {
  __shared__ __align__(16) unsigned short GS[24576];
  unsigned short* Asb = GS;
  unsigned short* Bsb = GS + 12288;
  const int tid = threadIdx.x;
  const int lane = tid & 63, wv = tid >> 6;
  const int g = lane >> 4, c = lane & 15;
  const int wr = wv >> 1, wc = wv & 1;
  const int am0 = blockIdx.x * 128;
  const int bn0 = blockIdx.y * 128;

  f32x4 acc[4][4];
  #pragma unroll
  for (int m = 0; m < 4; m++)
    #pragma unroll
    for (int n = 0; n < 4; n++) acc[m][n] = (f32x4){0.f, 0.f, 0.f, 0.f};

  const int srow = (lane >> 2);
  const int schunk = (lane & 3) ^ (srow & 3);

#define GSTAGE(buf, k0s)                                                       \
  do {                                                                         \
    _Pragma("unroll")                                                          \
    for (int i = 0; i < 2; ++i) {                                              \
      int row = i * 64 + wv * 16 + srow;                                       \
      __builtin_amdgcn_global_load_lds(                                        \
          (const __attribute__((address_space(1))) void*)(                     \
              A + (size_t)(am0 + row) * 1024 + (k0s) + schunk * 8),            \
          (__attribute__((address_space(3))) void*)(Asb + (buf)*4096 +         \
              (i * 64 + wv * 16) * 32),                                        \
          16, 0, 0);                                                           \
      __builtin_amdgcn_global_load_lds(                                        \
          (const __attribute__((address_space(1))) void*)(                     \
              Bt + (size_t)(bn0 + row) * 1024 + (k0s) + schunk * 8),           \
          (__attribute__((address_space(3))) void*)(Bsb + (buf)*4096 +         \
              (i * 64 + wv * 16) * 32),                                        \
          16, 0, 0);                                                           \
    }                                                                          \
  } while (0)

  GSTAGE(0, 0);
  GSTAGE(1, 32);
  asm volatile("s_waitcnt vmcnt(4)" ::: "memory");
  __builtin_amdgcn_s_barrier();
  __builtin_amdgcn_sched_barrier(0);

  for (int kt = 0; kt < 32; ++kt) {
    const int cur = kt % 3;
    s16x8 af[4], bfr[4];
    #pragma unroll
    for (int m = 0; m < 4; m++) {
      int R = wr * 64 + m * 16 + c;
      af[m] = *(const s16x8*)&Asb[cur * 4096 + R * 32 + ((g ^ (R & 3)) << 3)];
    }
    #pragma unroll
    for (int n = 0; n < 4; n++) {
      int R = wc * 64 + n * 16 + c;
      bfr[n] = *(const s16x8*)&Bsb[cur * 4096 + R * 32 + ((g ^ (R & 3)) << 3)];
    }
    if (kt < 30) GSTAGE((kt + 2) % 3, (kt + 2) * 32);
    __builtin_amdgcn_s_setprio(1);
    #pragma unroll
    for (int m = 0; m < 4; m++)
      #pragma unroll
      for (int n = 0; n < 4; n++)
        acc[m][n] = __builtin_amdgcn_mfma_f32_16x16x32_bf16(af[m], bfr[n], acc[m][n], 0, 0, 0);
    __builtin_amdgcn_s_setprio(0);
    __builtin_amdgcn_sched_barrier(0);
    asm volatile("s_waitcnt lgkmcnt(0)" ::: "memory");
    if (kt < 30) {
      asm volatile("s_waitcnt vmcnt(4)" ::: "memory");
    } else if (kt == 30) {
      asm volatile("s_waitcnt vmcnt(0)" ::: "memory");
    }
    __builtin_amdgcn_sched_barrier(0);
    __builtin_amdgcn_s_barrier();
    __builtin_amdgcn_sched_barrier(0);
  }
#undef GSTAGE

  #pragma unroll
  for (int m = 0; m < 4; m++) {
    #pragma unroll
    for (int n = 0; n < 4; n++) {
      f32x4 v = acc[m][n];
      int colg = bn0 + wc * 64 + n * 16 + c;
      #pragma unroll
      for (int r = 0; r < 4; ++r) {
        int row = am0 + wr * 64 + m * 16 + g * 4 + r;
        Cf[(size_t)row * 1024 + colg] = v[r];
      }
    }
  }
}

// ---------------------------------------------------------------------------
// Flash attention (round-8/10/13/14 PASSING kernel, byte-identical).
// ---------------------------------------------------------------------------
__global__ __launch_bounds__(512, 2) void attn_kernel(
    const unsigned short* __restrict__ Qh, const unsigned short* __restrict__ Kh,
    const unsigned short* __restrict__ Vt, unsigned short* __restrict__ heads) {
  __shared__ unsigned short Ks[2][128 * 64];
  __shared__ unsigned short Vs[3][64 * 128];
  const int tid = threadIdx.x;
  const int lane = tid & 63, wv = tid >> 6;
  const int g = lane >> 4, c = lane & 15;
  const int c7 = c & 7;
  const int xcd = blockIdx.x & 7, idx = blockIdx.x >> 3;
  const int bh = xcd * 4 + (idx >> 3), qb = idx & 7;
  const int b = bh >> 4, h = bh & 15;
  const int q0 = qb * 256 + wv * 32;

  const unsigned short* Qbase = Qh + ((size_t)bh * N_ + q0) * D_;
  const unsigned short* Kbase = Kh + (size_t)bh * N_ * D_;
  const unsigned short* Vbase = Vt + (size_t)bh * D_ * N_;

  s16x8 qfrag[2][2];
  #pragma unroll
  for (int qf = 0; qf < 2; ++qf)
    #pragma unroll
    for (int dblk = 0; dblk < 2; ++dblk)
      qfrag[qf][dblk] =
          *(const s16x8*)&Qbase[(size_t)(qf * 16 + c) * D_ + dblk * 32 + g * 8];

  s16x8 ones;
  #pragma unroll
  for (int j = 0; j < 8; ++j) ones[j] = (short)0x3F80;

  f32x4 O[2][4];
  f32x4 L[2];
  #pragma unroll
  for (int qf = 0; qf < 2; ++qf) {
    #pragma unroll
    for (int db = 0; db < 4; ++db) O[qf][db] = (f32x4){0.f, 0.f, 0.f, 0.f};
    L[qf] = (f32x4){0.f, 0.f, 0.f, 0.f};
  }

#define STAGE(kbuf, vbuf, t)                                                   \
  do {                                                                         \
    const int kv0s = (t) * 128;                                                \
    _Pragma("unroll")                                                          \
    for (int i = 0; i < 2; ++i) {                                              \
      int row = i * 64 + wv * 8 + (lane >> 3);                                 \
      int un = (lane & 7) ^ (row & 7);                                         \
      __builtin_amdgcn_global_load_lds(                                        \
          (const __attribute__((address_space(1))) void*)(Kbase +              \
              (size_t)(kv0s + row) * 64 + un * 8),                             \
          (__attribute__((address_space(3))) void*)(&Ks[kbuf][(i * 512 + wv * 64) * 8]), \
          16, 0, 0);                                                           \
    }                                                                          \
    _Pragma("unroll")                                                          \
    for (int i = 0; i < 2; ++i) {                                              \
      int vrow = i * 32 + wv * 4 + (lane >> 4);                                \
      int un = (lane & 15) ^ (vrow & 15);                                      \
      __builtin_amdgcn_global_load_lds(                                        \
          (const __attribute__((address_space(1))) void*)(Vbase +              \
              (size_t)vrow * N_ + kv0s + un * 8),                              \
          (__attribute__((address_space(3))) void*)(&Vs[vbuf][(i * 512 + wv * 64) * 8]), \
          16, 0, 0);                                                           \
    }                                                                          \
  } while (0)

#define PVSTEP(VBUF, PF)                                                       \
  do {                                                                         \
    _Pragma("unroll")                                                          \
    for (int km = 0; km < 4; ++km) {                                           \
      union { u32x4 u; s16x8 s; } b0_, b1_;                                    \
      b0_.u = (u32x4){PF[0][km][0], PF[0][km][1], PF[0][km][2], PF[0][km][3]}; \
      b1_.u = (u32x4){PF[1][km][0], PF[1][km][1], PF[1][km][2], PF[1][km][3]}; \
      _Pragma("unroll")                                                        \
      for (int db = 0; db < 4; ++db) {                                         \
        s16x8 vf = *(const s16x8*)&Vs[VBUF][(db * 16 + c) * 128 +              \
                                           (((km * 4 + g) ^ c) << 3)];         \
        O[0][db] = __builtin_amdgcn_mfma_f32_16x16x32_bf16(vf, b0_.s, O[0][db], 0, 0, 0); \
        O[1][db] = __builtin_amdgcn_mfma_f32_16x16x32_bf16(vf, b1_.s, O[1][db], 0, 0, 0); \
      }                                                                        \
      L[0] = __builtin_amdgcn_mfma_f32_16x16x32_bf16(ones, b0_.s, L[0], 0, 0, 0); \
      L[1] = __builtin_amdgcn_mfma_f32_16x16x32_bf16(ones, b1_.s, L[1], 0, 0, 0); \
    }                                                                          \
  } while (0)

  u32 pf[2][4][4], pfp[2][4][4];

  STAGE(0, 0, 0);
  __syncthreads();

  #pragma unroll
  for (int t = 0; t < 16; ++t) {
    const int kcur = t & 1;
    if (t < 15) STAGE((t + 1) & 1, (t + 1) % 3, t + 1);

    f32x4 st[2][8];
    __builtin_amdgcn_s_setprio(1);
    #pragma unroll
    for (int kb = 0; kb < 8; ++kb) {
      s16x8 k0 = *(const s16x8*)&Ks[kcur][(kb * 16 + c) * 64 + ((g ^ c7) << 3)];
      s16x8 k1 = *(const s16x8*)&Ks[kcur][(kb * 16 + c) * 64 + (((4 + g) ^ c7) << 3)];
      #pragma unroll
      for (int qf = 0; qf < 2; ++qf) {
        f32x4 z = (f32x4){0.f, 0.f, 0.f, 0.f};
        z = __builtin_amdgcn_mfma_f32_16x16x32_bf16(k0, qfrag[qf][0], z, 0, 0, 0);
        st[qf][kb] = __builtin_amdgcn_mfma_f32_16x16x32_bf16(k1, qfrag[qf][1], z, 0, 0, 0);
      }
    }
    __builtin_amdgcn_s_setprio(0);

    if (t > 0) {
      PVSTEP((t + 2) % 3, pfp);
    }

    #pragma unroll
    for (int qf = 0; qf < 2; ++qf) {
      #pragma unroll
      for (int kb = 0; kb < 8; ++kb)
        #pragma unroll
        for (int r = 0; r < 4; ++r)
          st[qf][kb][r] = __builtin_amdgcn_exp2f(st[qf][kb][r]);

      #pragma unroll
      for (int km = 0; km < 4; ++km) {
        u32 x00, x01, x10, x11;
        asm("v_cvt_pk_bf16_f32 %0, %1, %2" : "=v"(x00) : "v"(st[qf][2 * km][0]), "v"(st[qf][2 * km][1]));
        asm("v_cvt_pk_bf16_f32 %0, %1, %2" : "=v"(x01) : "v"(st[qf][2 * km][2]), "v"(st[qf][2 * km][3]));
        asm("v_cvt_pk_bf16_f32 %0, %1, %2" : "=v"(x10) : "v"(st[qf][2 * km + 1][0]), "v"(st[qf][2 * km + 1][1]));
        asm("v_cvt_pk_bf16_f32 %0, %1, %2" : "=v"(x11) : "v"(st[qf][2 * km + 1][2]), "v"(st[qf][2 * km + 1][3]));
        asm("v_permlane32_swap_b32 %0, %1" : "+v"(x00), "+v"(x10));
        asm("v_permlane32_swap_b32 %0, %1" : "+v"(x01), "+v"(x11));
        asm("v_permlane16_swap_b32 %0, %1" : "+v"(x00), "+v"(x10));
        asm("v_permlane16_swap_b32 %0, %1" : "+v"(x01), "+v"(x11));
        pf[qf][km][0] = x00; pf[qf][km][1] = x01;
        pf[qf][km][2] = x10; pf[qf][km][3] = x11;
      }
    }

    #pragma unroll
    for (int qf = 0; qf < 2; ++qf)
      #pragma unroll
      for (int km = 0; km < 4; ++km)
        #pragma unroll
        for (int j = 0; j < 4; ++j) pfp[qf][km][j] = pf[qf][km][j];

    __syncthreads();
  }

  __builtin_amdgcn_s_setprio(1);
  PVSTEP(0, pfp);
  __builtin_amdgcn_s_setprio(0);
#undef STAGE
#undef PVSTEP

  #pragma unroll
  for (int qf = 0; qf < 2; ++qf) {
    float linv = 1.0f / L[qf][0];
    size_t rowoff = ((size_t)(b * N_ + q0 + qf * 16 + c)) * C_ + h * 64;
    #pragma unroll
    for (int db = 0; db < 4; ++db) {
      u32 d0, d1;
      float v0 = O[qf][db][0] * linv, v1 = O[qf][db][1] * linv;
      float v2 = O[qf][db][2] * linv, v3 = O[qf][db][3] * linv;
      asm("v_cvt_pk_bf16_f32 %0, %1, %2" : "=v"(d0) : "v"(v0), "v"(v1));
      asm("v_cvt_pk_bf16_f32 %0, %1, %2" : "=v"(d1) : "v"(v2), "v"(v3));
      uint2 st2; st2.x = d0; st2.y = d1;
      *(uint2*)&heads[rowoff + db * 16 + g * 4] = st2;
    }
  }
}

// ---------------------------------------------------------------------------
extern "C" void kernel_launch(void* const* d_in, const int* in_sizes, int n_in,
                              void* d_out, int out_size, void* d_ws, size_t ws_size,
                              hipStream_t stream) {
  const float* x  = (const float*)d_in[0];
  const float* Wq = (const float*)d_in[1];
  const float* Wk = (const float*)d_in[2];
  const float* Wv = (const float*)d_in[3];
  const float* Wo = (const float*)d_in[4];
  float* out = (float*)d_out;

  char* ws = (char*)d_ws;
  unsigned short* WtQKV = (unsigned short*)(ws);
  unsigned short* WtO   = (unsigned short*)(ws + 6291456);
  unsigned short* Qh    = (unsigned short*)(ws + 8388608);
  unsigned short* Kh    = (unsigned short*)(ws + 16777216);
  unsigned short* Vt    = (unsigned short*)(ws + 25165824);
  unsigned short* heads = (unsigned short*)(ws + 33554432);
  unsigned short* xb    = (unsigned short*)(ws + 33554432);  // aliases heads

  wtrans_kernel<<<dim3(3072), dim3(256), 0, stream>>>(Wq, Wk, Wv, Wo, WtQKV, WtO, x, xb);
  gemm0_kernel<<<dim3(16, 12), dim3(512), 0, stream>>>(xb, WtQKV, Qh, Kh, Vt);
  attn_kernel<<<dim3(256), dim3(512), 0, stream>>>(Qh, Kh, Vt, heads);
  gemm1_kernel<<<dim3(32, 8), dim3(256), 0, stream>>>(heads, WtO, out);
}

// Round 16
// 96.395 us; speedup vs baseline: 1.0152x; 1.0152x over previous
//
#include <hip/hip_runtime.h>

typedef __attribute__((ext_vector_type(4))) float f32x4;
typedef __attribute__((ext_vector_type(8))) short s16x8;
typedef unsigned int u32;
typedef __attribute__((ext_vector_type(4))) unsigned int u32x4;

#define B_ 2
#define N_ 2048
#define C_ 1024
#define H_ 16
#define D_ 64

__device__ __forceinline__ unsigned short f2bf(float f) {
  union { float f; unsigned u; } v; v.f = f;
  unsigned r = v.u + 0x7fffu + ((v.u >> 16) & 1u);
  return (unsigned short)(r >> 16);
}

// ---------------------------------------------------------------------------
// Blocks [0,1024): transpose + convert weights to bf16 (Wq gets 1/8*log2e).
// Blocks [1024,3072): convert x (f32) -> xb (bf16), 2048 elems/block.
// ---------------------------------------------------------------------------
__global__ __launch_bounds__(256) void wtrans_kernel(
    const float* __restrict__ Wq, const float* __restrict__ Wk,
    const float* __restrict__ Wv, const float* __restrict__ Wo,
    unsigned short* __restrict__ WtQKV, unsigned short* __restrict__ WtO,
    const float* __restrict__ xsrc, unsigned short* __restrict__ xb) {
  const int t = threadIdx.x;
  if (blockIdx.x >= 1024) {
    int i = (blockIdx.x - 1024) * 2048 + t * 8;
    float4 f0 = *(const float4*)&xsrc[i];
    float4 f1 = *(const float4*)&xsrc[i + 4];
    u32 p0, p1, p2, p3;
    asm("v_cvt_pk_bf16_f32 %0, %1, %2" : "=v"(p0) : "v"(f0.x), "v"(f0.y));
    asm("v_cvt_pk_bf16_f32 %0, %1, %2" : "=v"(p1) : "v"(f0.z), "v"(f0.w));
    asm("v_cvt_pk_bf16_f32 %0, %1, %2" : "=v"(p2) : "v"(f1.x), "v"(f1.y));
    asm("v_cvt_pk_bf16_f32 %0, %1, %2" : "=v"(p3) : "v"(f1.z), "v"(f1.w));
    uint4 o; o.x = p0; o.y = p1; o.z = p2; o.w = p3;
    *(uint4*)&xb[i] = o;
    return;
  }
  __shared__ float lds[64][65];
  const int w = blockIdx.x >> 8;
  const int tile = blockIdx.x & 255;
  const int c0 = (tile >> 4) * 64, d0 = (tile & 15) * 64;
  const float* W = (w == 0) ? Wq : (w == 1) ? Wk : (w == 2) ? Wv : Wo;
  const float scale = (w == 0) ? 0.125f * 1.4426950408889634f : 1.0f;
  #pragma unroll
  for (int p = 0; p < 16; ++p) {
    int i = p * 256 + t; int r = i >> 6, cc = i & 63;
    lds[r][cc] = W[(size_t)(c0 + r) * 1024 + d0 + cc];
  }
  __syncthreads();
  #pragma unroll
  for (int p = 0; p < 16; ++p) {
    int i = p * 256 + t; int r = i >> 6, cc = i & 63;
    unsigned short v = f2bf(lds[cc][r] * scale);
    if (w < 3) WtQKV[(size_t)(w * 1024 + d0 + r) * 1024 + c0 + cc] = v;
    else       WtO[(size_t)(d0 + r) * 1024 + c0 + cc] = v;
  }
}

// ---------------------------------------------------------------------------
// gemm0: 256x256-tile 8-phase pipelined GEMM (QKV projection), r14-verified.
// C[4096][3072] = xb[4096][1024] * WtQKV[3072][1024]^T.
// 8 waves (2M x 4N); LDS 128KB A0|A1|B0|B1 (3-bit XOR swizzle); per-phase
// half-tile stage; vmcnt(6) at phases 4/8 only. Q/K scalar-scatter epilogue
// (r15's LDS-transpose variant measured slower); V-tiles transpose via
// swizzled LDS -> b128 Vt rows.
// ---------------------------------------------------------------------------
__global__ __launch_bounds__(512, 2) void gemm0_kernel(
    const unsigned short* __restrict__ A, const unsigned short* __restrict__ Bt,
    unsigned short* __restrict__ Qh, unsigned short* __restrict__ Kh,
    unsigned short* __restrict__ Vt) {
  __shared__ __align__(16) unsigned short GS[65536];  // 128KB
  const int tid = threadIdx.x;
  const int lane = tid & 63, wv = tid >> 6;
  const int g = lane >> 4, c = lane & 15;
  const int c7 = c & 7;
  const int wr = wv >> 2, wc = wv & 3;  // 2M x 4N
  const int am0 = blockIdx.x * 256;
  const int bn0 = blockIdx.y * 256;
  const int srow8 = lane >> 3;
  const int schunk = (lane & 7) ^ (srow8 & 7);  // involution source swizzle

  enum { A0o = 0, A1o = 16384, B0o = 32768, B1o = 49152 };

  f32x4 acc[8][4];
  #pragma unroll
  for (int m = 0; m < 8; ++m)
    #pragma unroll
    for (int n = 0; n < 4; ++n) acc[m][n] = (f32x4){0.f, 0.f, 0.f, 0.f};

  s16x8 af[4][2];
  s16x8 bfr[4][2];

#define STAGE(P, rb, ldsOff, h, kslab)                                         \
  do {                                                                         \
    _Pragma("unroll")                                                          \
    for (int i_ = 0; i_ < 2; ++i_) {                                           \
      __builtin_amdgcn_global_load_lds(                                        \
          (const __attribute__((address_space(1))) void*)(                     \
              (P) + (size_t)((rb) + (h) * 128 + i_ * 64 + wv * 8 + srow8) *    \
                        1024 + (kslab) * 64 + schunk * 8),                     \
          (__attribute__((address_space(3))) void*)(GS + (ldsOff) +            \
              ((h) * 128 + i_ * 64 + wv * 8) * 64),                            \
          16, 0, 0);                                                           \
    }                                                                          \
  } while (0)

#define LDA(bufOff, mh)                                                        \
  do {                                                                         \
    _Pragma("unroll")                                                          \
    for (int mm = 0; mm < 4; ++mm)                                             \
      _Pragma("unroll")                                                        \
      for (int kk = 0; kk < 2; ++kk)                                           \
        af[mm][kk] = *(const s16x8*)&GS[(bufOff) +                             \
            (((mh) * 4 + mm) * 32 + wr * 16 + c) * 64 +                        \
            (((kk * 4 + g) ^ c7) << 3)];                                       \
  } while (0)

#define LDB(bufOff, nh)                                                        \
  do {                                                                         \
    _Pragma("unroll")                                                          \
    for (int nn = 0; nn < 2; ++nn)                                             \
      _Pragma("unroll")                                                        \
      for (int kk = 0; kk < 2; ++kk)                                           \
        bfr[(nh) * 2 + nn][kk] = *(const s16x8*)&GS[(bufOff) +                 \
            ((((nh) * 2 + nn) * 64 + wc * 16 + c)) * 64 +                      \
            (((kk * 4 + g) ^ c7) << 3)];                                       \
  } while (0)

#define MM(mh, nh)                                                             \
  do {                                                                         \
    __builtin_amdgcn_s_setprio(1);                                             \
    _Pragma("unroll")                                                          \
    for (int mm = 0; mm < 4; ++mm)                                             \
      _Pragma("unroll")                                                        \
      for (int nn = 0; nn < 2; ++nn)                                           \
        _Pragma("unroll")                                                      \
        for (int kk = 0; kk < 2; ++kk)                                         \
          acc[(mh) * 4 + mm][(nh) * 2 + nn] =                                  \
              __builtin_amdgcn_mfma_f32_16x16x32_bf16(                         \
                  af[mm][kk], bfr[(nh) * 2 + nn][kk],                          \
                  acc[(mh) * 4 + mm][(nh) * 2 + nn], 0, 0, 0);                 \
    __builtin_amdgcn_s_setprio(0);                                             \
  } while (0)

#define BAR() __builtin_amdgcn_s_barrier()
#define LGKM0() asm volatile("s_waitcnt lgkmcnt(0)" ::: "memory")

  STAGE(A, am0, A0o, 0, 0);
  STAGE(Bt, bn0, B0o, 0, 0);
  STAGE(A, am0, A0o, 1, 0);
  STAGE(Bt, bn0, B0o, 1, 0);
  STAGE(A, am0, A1o, 0, 1);
  STAGE(Bt, bn0, B1o, 0, 1);
  STAGE(A, am0, A1o, 1, 1);
  asm volatile("s_waitcnt vmcnt(6)" ::: "memory");
  BAR();

  for (int it = 0; it < 8; ++it) {
    const int kc = 2 * it + 2, kd = 2 * it + 3;
    const bool more = (it < 7);
    LDA(A0o, 0); LDB(B0o, 0);
    STAGE(Bt, bn0, B1o, 1, 2 * it + 1);
    BAR(); LGKM0(); MM(0, 0); BAR();
    LDB(B0o, 1);
    if (more) STAGE(A, am0, A0o, 0, kc);
    BAR(); LGKM0(); MM(0, 1); BAR();
    LDA(A0o, 1);
    if (more) STAGE(Bt, bn0, B0o, 0, kc);
    BAR(); LGKM0(); MM(1, 0); BAR();
    if (more) {
      STAGE(A, am0, A0o, 1, kc);
      asm volatile("s_waitcnt vmcnt(6)" ::: "memory");
    } else {
      asm volatile("s_waitcnt vmcnt(0)" ::: "memory");
    }
    BAR(); LGKM0(); MM(1, 1); BAR();
    LDA(A1o, 0); LDB(B1o, 0);
    if (more) STAGE(Bt, bn0, B0o, 1, kc);
    BAR(); LGKM0(); MM(0, 0); BAR();
    LDB(B1o, 1);
    if (more) STAGE(A, am0, A1o, 0, kd);
    BAR(); LGKM0(); MM(0, 1); BAR();
    LDA(A1o, 1);
    if (more) STAGE(Bt, bn0, B1o, 0, kd);
    BAR(); LGKM0(); MM(1, 0); BAR();
    if (more) {
      STAGE(A, am0, A1o, 1, kd);
      asm volatile("s_waitcnt vmcnt(6)" ::: "memory");
    }
    BAR(); LGKM0(); MM(1, 1); BAR();
  }
#undef STAGE
#undef LDA
#undef LDB
#undef MM
#undef BAR
#undef LGKM0

  const bool vblock = (blockIdx.y >= 8);
  if (!vblock) {
    #pragma unroll
    for (int m = 0; m < 8; ++m) {
      #pragma unroll
      for (int n = 0; n < 4; ++n) {
        f32x4 v = acc[m][n];
        int colg = bn0 + n * 64 + wc * 16 + c;
        int tensor = colg >> 10, cc = colg & 1023;
        int hh = cc >> 6, dd = cc & 63;
        #pragma unroll
        for (int r = 0; r < 4; ++r) {
          int row = am0 + m * 32 + wr * 16 + g * 4 + r;
          int bb = row >> 11, tok = row & 2047;
          unsigned short val = f2bf(v[r]);
          if (tensor == 0)
            Qh[(((size_t)bb * H_ + hh) * N_ + tok) * D_ + dd] = val;
          else
            Kh[(((size_t)bb * H_ + hh) * N_ + tok) * D_ + dd] = val;
        }
      }
    }
  } else {
    // V-tile: transpose 256x256 through swizzled LDS, b128 Vt row writes.
    __syncthreads();  // staging dead; GS becomes the transpose buffer
    #pragma unroll
    for (int m = 0; m < 8; ++m) {
      #pragma unroll
      for (int n = 0; n < 4; ++n) {
        f32x4 v = acc[m][n];
        int lc = n * 64 + wc * 16 + c;
        #pragma unroll
        for (int r = 0; r < 4; ++r) {
          int lr = m * 32 + wr * 16 + g * 4 + r;
          GS[lc * 256 + ((((lr >> 3) ^ (lc & 31)) << 3) | (lr & 7))] = f2bf(v[r]);
        }
      }
    }
    __syncthreads();
    const int chl = tid & 31, rowb = tid >> 5;  // 32 chunks x 16 row-groups
    const int tok0 = (am0 & 2047) + chl * 8;
    const int bb = am0 >> 11;
    #pragma unroll
    for (int j = 0; j < 16; ++j) {
      int ddl = j * 16 + rowb;
      s16x8 val = *(const s16x8*)&GS[ddl * 256 + ((chl ^ (ddl & 31)) << 3)];
      int vcol = bn0 - 2048 + ddl;
      int hh = vcol >> 6, dd = vcol & 63;
      *(s16x8*)&Vt[(((size_t)bb * H_ + hh) * D_ + dd) * N_ + tok0] = val;
    }
  }
}

// ---------------------------------------------------------------------------
// gemm1 (r13/r14-verified): out[4096][1024] = heads * WtO^T.
// 128x128 tile, BK=32, tri-buffered counted-vmcnt pipeline.
// ---------------------------------------------------------------------------
__global__ __launch_bounds__(256, 3) void gemm1_kernel(
    const unsigned short* __restrict__ A, const unsigned short* __restrict__ Bt,
    float* __restrict__ Cf) {
  __shared__ __align__(16) unsigned short GS[24576];
  unsigned short* Asb = GS;
  unsigned short* Bsb = GS + 12288;
  const int tid = threadIdx.x;
  const int lane = tid & 63, wv = tid >> 6;
  const int g = lane >> 4, c = lane & 15;
  const int wr = wv >> 1, wc = wv & 1;
  const int am0 = blockIdx.x * 128;
  const int bn0 = blockIdx.y * 128;

  f32x4 acc[4][4];
  #pragma unroll
  for (int m = 0; m < 4; m++)
    #pragma unroll
    for (int n = 0; n < 4; n++) acc[m][n] = (f32x4){0.f, 0.f, 0.f, 0.f};

  const int srow = (lane >> 2);
  const int schunk = (lane & 3) ^ (srow & 3);

#define GSTAGE(buf, k0s)                                                       \
  do {                                                                         \
    _Pragma("unroll")                                                          \
    for (int i = 0; i < 2; ++i) {                                              \
      int row = i * 64 + wv * 16 + srow;                                       \
      __builtin_amdgcn_global_load_lds(                                        \
          (const __attribute__((address_space(1))) void*)(                     \
              A + (size_t)(am0 + row) * 1024 + (k0s) + schunk * 8),            \
          (__attribute__((address_space(3))) void*)(Asb + (buf)*4096 +         \
              (i * 64 + wv * 16) * 32),                                        \
          16, 0, 0);                                                           \
      __builtin_amdgcn_global_load_lds(                                        \
          (const __attribute__((address_space(1))) void*)(                     \
              Bt + (size_t)(bn0 + row) * 1024 + (k0s) + schunk * 8),           \
          (__attribute__((address_space(3))) void*)(Bsb + (buf)*4096 +         \
              (i * 64 + wv * 16) * 32),                                        \
          16, 0, 0);                                                           \
    }                                                                          \
  } while (0)

  GSTAGE(0, 0);
  GSTAGE(1, 32);
  asm volatile("s_waitcnt vmcnt(4)" ::: "memory");
  __builtin_amdgcn_s_barrier();
  __builtin_amdgcn_sched_barrier(0);

  for (int kt = 0; kt < 32; ++kt) {
    const int cur = kt % 3;
    s16x8 af[4], bfr[4];
    #pragma unroll
    for (int m = 0; m < 4; m++) {
      int R = wr * 64 + m * 16 + c;
      af[m] = *(const s16x8*)&Asb[cur * 4096 + R * 32 + ((g ^ (R & 3)) << 3)];
    }
    #pragma unroll
    for (int n = 0; n < 4; n++) {
      int R = wc * 64 + n * 16 + c;
      bfr[n] = *(const s16x8*)&Bsb[cur * 4096 + R * 32 + ((g ^ (R & 3)) << 3)];
    }
    if (kt < 30) GSTAGE((kt + 2) % 3, (kt + 2) * 32);
    __builtin_amdgcn_s_setprio(1);
    #pragma unroll
    for (int m = 0; m < 4; m++)
      #pragma unroll
      for (int n = 0; n < 4; n++)
        acc[m][n] = __builtin_amdgcn_mfma_f32_16x16x32_bf16(af[m], bfr[n], acc[m][n], 0, 0, 0);
    __builtin_amdgcn_s_setprio(0);
    __builtin_amdgcn_sched_barrier(0);
    asm volatile("s_waitcnt lgkmcnt(0)" ::: "memory");
    if (kt < 30) {
      asm volatile("s_waitcnt vmcnt(4)" ::: "memory");
    } else if (kt == 30) {
      asm volatile("s_waitcnt vmcnt(0)" ::: "memory");
    }
    __builtin_amdgcn_sched_barrier(0);
    __builtin_amdgcn_s_barrier();
    __builtin_amdgcn_sched_barrier(0);
  }
#undef GSTAGE

  #pragma unroll
  for (int m = 0; m < 4; m++) {
    #pragma unroll
    for (int n = 0; n < 4; n++) {
      f32x4 v = acc[m][n];
      int colg = bn0 + wc * 64 + n * 16 + c;
      #pragma unroll
      for (int r = 0; r < 4; ++r) {
        int row = am0 + wr * 64 + m * 16 + g * 4 + r;
        Cf[(size_t)row * 1024 + colg] = v[r];
      }
    }
  }
}

// ---------------------------------------------------------------------------
// Flash attention (round-8/10/13/14 PASSING kernel, byte-identical): 8 waves
// x 32 q-rows, KVBLK=128, 16 tiles, grid 256 (4 heads/XCD). Chainless softmax
// (no max tracking, lsum via ones-MFMA), T15 PV(t-1) pipeline, K dbuf /
// V 3-buf.
// ---------------------------------------------------------------------------
__global__ __launch_bounds__(512, 2) void attn_kernel(
    const unsigned short* __restrict__ Qh, const unsigned short* __restrict__ Kh,
    const unsigned short* __restrict__ Vt, unsigned short* __restrict__ heads) {
  __shared__ unsigned short Ks[2][128 * 64];
  __shared__ unsigned short Vs[3][64 * 128];
  const int tid = threadIdx.x;
  const int lane = tid & 63, wv = tid >> 6;
  const int g = lane >> 4, c = lane & 15;
  const int c7 = c & 7;
  const int xcd = blockIdx.x & 7, idx = blockIdx.x >> 3;
  const int bh = xcd * 4 + (idx >> 3), qb = idx & 7;
  const int b = bh >> 4, h = bh & 15;
  const int q0 = qb * 256 + wv * 32;

  const unsigned short* Qbase = Qh + ((size_t)bh * N_ + q0) * D_;
  const unsigned short* Kbase = Kh + (size_t)bh * N_ * D_;
  const unsigned short* Vbase = Vt + (size_t)bh * D_ * N_;

  s16x8 qfrag[2][2];
  #pragma unroll
  for (int qf = 0; qf < 2; ++qf)
    #pragma unroll
    for (int dblk = 0; dblk < 2; ++dblk)
      qfrag[qf][dblk] =
          *(const s16x8*)&Qbase[(size_t)(qf * 16 + c) * D_ + dblk * 32 + g * 8];

  s16x8 ones;
  #pragma unroll
  for (int j = 0; j < 8; ++j) ones[j] = (short)0x3F80;

  f32x4 O[2][4];
  f32x4 L[2];
  #pragma unroll
  for (int qf = 0; qf < 2; ++qf) {
    #pragma unroll
    for (int db = 0; db < 4; ++db) O[qf][db] = (f32x4){0.f, 0.f, 0.f, 0.f};
    L[qf] = (f32x4){0.f, 0.f, 0.f, 0.f};
  }

#define STAGE(kbuf, vbuf, t)                                                   \
  do {                                                                         \
    const int kv0s = (t) * 128;                                                \
    _Pragma("unroll")                                                          \
    for (int i = 0; i < 2; ++i) {                                              \
      int row = i * 64 + wv * 8 + (lane >> 3);                                 \
      int un = (lane & 7) ^ (row & 7);                                         \
      __builtin_amdgcn_global_load_lds(                                        \
          (const __attribute__((address_space(1))) void*)(Kbase +              \
              (size_t)(kv0s + row) * 64 + un * 8),                             \
          (__attribute__((address_space(3))) void*)(&Ks[kbuf][(i * 512 + wv * 64) * 8]), \
          16, 0, 0);                                                           \
    }                                                                          \
    _Pragma("unroll")                                                          \
    for (int i = 0; i < 2; ++i) {                                              \
      int vrow = i * 32 + wv * 4 + (lane >> 4);                                \
      int un = (lane & 15) ^ (vrow & 15);                                      \
      __builtin_amdgcn_global_load_lds(                                        \
          (const __attribute__((address_space(1))) void*)(Vbase +              \
              (size_t)vrow * N_ + kv0s + un * 8),                              \
          (__attribute__((address_space(3))) void*)(&Vs[vbuf][(i * 512 + wv * 64) * 8]), \
          16, 0, 0);                                                           \
    }                                                                          \
  } while (0)

#define PVSTEP(VBUF, PF)                                                       \
  do {                                                                         \
    _Pragma("unroll")                                                          \
    for (int km = 0; km < 4; ++km) {                                           \
      union { u32x4 u; s16x8 s; } b0_, b1_;                                    \
      b0_.u = (u32x4){PF[0][km][0], PF[0][km][1], PF[0][km][2], PF[0][km][3]}; \
      b1_.u = (u32x4){PF[1][km][0], PF[1][km][1], PF[1][km][2], PF[1][km][3]}; \
      _Pragma("unroll")                                                        \
      for (int db = 0; db < 4; ++db) {                                         \
        s16x8 vf = *(const s16x8*)&Vs[VBUF][(db * 16 + c) * 128 +              \
                                           (((km * 4 + g) ^ c) << 3)];         \
        O[0][db] = __builtin_amdgcn_mfma_f32_16x16x32_bf16(vf, b0_.s, O[0][db], 0, 0, 0); \
        O[1][db] = __builtin_amdgcn_mfma_f32_16x16x32_bf16(vf, b1_.s, O[1][db], 0, 0, 0); \
      }                                                                        \
      L[0] = __builtin_amdgcn_mfma_f32_16x16x32_bf16(ones, b0_.s, L[0], 0, 0, 0); \
      L[1] = __builtin_amdgcn_mfma_f32_16x16x32_bf16(ones, b1_.s, L[1], 0, 0, 0); \
    }                                                                          \
  } while (0)

  u32 pf[2][4][4], pfp[2][4][4];

  STAGE(0, 0, 0);
  __syncthreads();

  #pragma unroll
  for (int t = 0; t < 16; ++t) {
    const int kcur = t & 1;
    if (t < 15) STAGE((t + 1) & 1, (t + 1) % 3, t + 1);

    f32x4 st[2][8];
    __builtin_amdgcn_s_setprio(1);
    #pragma unroll
    for (int kb = 0; kb < 8; ++kb) {
      s16x8 k0 = *(const s16x8*)&Ks[kcur][(kb * 16 + c) * 64 + ((g ^ c7) << 3)];
      s16x8 k1 = *(const s16x8*)&Ks[kcur][(kb * 16 + c) * 64 + (((4 + g) ^ c7) << 3)];
      #pragma unroll
      for (int qf = 0; qf < 2; ++qf) {
        f32x4 z = (f32x4){0.f, 0.f, 0.f, 0.f};
        z = __builtin_amdgcn_mfma_f32_16x16x32_bf16(k0, qfrag[qf][0], z, 0, 0, 0);
        st[qf][kb] = __builtin_amdgcn_mfma_f32_16x16x32_bf16(k1, qfrag[qf][1], z, 0, 0, 0);
      }
    }
    __builtin_amdgcn_s_setprio(0);

    if (t > 0) {
      PVSTEP((t + 2) % 3, pfp);
    }

    #pragma unroll
    for (int qf = 0; qf < 2; ++qf) {
      #pragma unroll
      for (int kb = 0; kb < 8; ++kb)
        #pragma unroll
        for (int r = 0; r < 4; ++r)
          st[qf][kb][r] = __builtin_amdgcn_exp2f(st[qf][kb][r]);

      #pragma unroll
      for (int km = 0; km < 4; ++km) {
        u32 x00, x01, x10, x11;
        asm("v_cvt_pk_bf16_f32 %0, %1, %2" : "=v"(x00) : "v"(st[qf][2 * km][0]), "v"(st[qf][2 * km][1]));
        asm("v_cvt_pk_bf16_f32 %0, %1, %2" : "=v"(x01) : "v"(st[qf][2 * km][2]), "v"(st[qf][2 * km][3]));
        asm("v_cvt_pk_bf16_f32 %0, %1, %2" : "=v"(x10) : "v"(st[qf][2 * km + 1][0]), "v"(st[qf][2 * km + 1][1]));
        asm("v_cvt_pk_bf16_f32 %0, %1, %2" : "=v"(x11) : "v"(st[qf][2 * km + 1][2]), "v"(st[qf][2 * km + 1][3]));
        asm("v_permlane32_swap_b32 %0, %1" : "+v"(x00), "+v"(x10));
        asm("v_permlane32_swap_b32 %0, %1" : "+v"(x01), "+v"(x11));
        asm("v_permlane16_swap_b32 %0, %1" : "+v"(x00), "+v"(x10));
        asm("v_permlane16_swap_b32 %0, %1" : "+v"(x01), "+v"(x11));
        pf[qf][km][0] = x00; pf[qf][km][1] = x01;
        pf[qf][km][2] = x10; pf[qf][km][3] = x11;
      }
    }

    #pragma unroll
    for (int qf = 0; qf < 2; ++qf)
      #pragma unroll
      for (int km = 0; km < 4; ++km)
        #pragma unroll
        for (int j = 0; j < 4; ++j) pfp[qf][km][j] = pf[qf][km][j];

    __syncthreads();
  }

  __builtin_amdgcn_s_setprio(1);
  PVSTEP(0, pfp);
  __builtin_amdgcn_s_setprio(0);
#undef STAGE
#undef PVSTEP

  #pragma unroll
  for (int qf = 0; qf < 2; ++qf) {
    float linv = 1.0f / L[qf][0];
    size_t rowoff = ((size_t)(b * N_ + q0 + qf * 16 + c)) * C_ + h * 64;
    #pragma unroll
    for (int db = 0; db < 4; ++db) {
      u32 d0, d1;
      float v0 = O[qf][db][0] * linv, v1 = O[qf][db][1] * linv;
      float v2 = O[qf][db][2] * linv, v3 = O[qf][db][3] * linv;
      asm("v_cvt_pk_bf16_f32 %0, %1, %2" : "=v"(d0) : "v"(v0), "v"(v1));
      asm("v_cvt_pk_bf16_f32 %0, %1, %2" : "=v"(d1) : "v"(v2), "v"(v3));
      uint2 st2; st2.x = d0; st2.y = d1;
      *(uint2*)&heads[rowoff + db * 16 + g * 4] = st2;
    }
  }
}

// ---------------------------------------------------------------------------
extern "C" void kernel_launch(void* const* d_in, const int* in_sizes, int n_in,
                              void* d_out, int out_size, void* d_ws, size_t ws_size,
                              hipStream_t stream) {
  const float* x  = (const float*)d_in[0];
  const float* Wq = (const float*)d_in[1];
  const float* Wk = (const float*)d_in[2];
  const float* Wv = (const float*)d_in[3];
  const float* Wo = (const float*)d_in[4];
  float* out = (float*)d_out;

  char* ws = (char*)d_ws;
  unsigned short* WtQKV = (unsigned short*)(ws);
  unsigned short* WtO   = (unsigned short*)(ws + 6291456);
  unsigned short* Qh    = (unsigned short*)(ws + 8388608);
  unsigned short* Kh    = (unsigned short*)(ws + 16777216);
  unsigned short* Vt    = (unsigned short*)(ws + 25165824);
  unsigned short* heads = (unsigned short*)(ws + 33554432);
  unsigned short* xb    = (unsigned short*)(ws + 33554432);  // aliases heads

  wtrans_kernel<<<dim3(3072), dim3(256), 0, stream>>>(Wq, Wk, Wv, Wo, WtQKV, WtO, x, xb);
  gemm0_kernel<<<dim3(16, 12), dim3(512), 0, stream>>>(xb, WtQKV, Qh, Kh, Vt);
  attn_kernel<<<dim3(256), dim3(512), 0, stream>>>(Qh, Kh, Vt, heads);
  gemm1_kernel<<<dim3(32, 8), dim3(256), 0, stream>>>(heads, WtO, out);
}